// Round 4
// baseline (540.836 us; speedup 1.0000x reference)
//
#include <hip/hip_runtime.h>
#include <hip/hip_bf16.h>

typedef unsigned short u16;
typedef short bf16x8 __attribute__((ext_vector_type(8)));
typedef float f32x4 __attribute__((ext_vector_type(4)));
typedef u16 u16x8 __attribute__((ext_vector_type(8)));
typedef u16 u16x4 __attribute__((ext_vector_type(4)));

#define S_TOK 4096
#define MDIM 1024
#define EDIM 8
#define FDIM 4096
#define CCAP 1024
#define HALF_F 2048

// ---- scratch in static device globals (200MB total) ----
__device__ __align__(16) u16   g_xb [S_TOK * MDIM];          // 8MB  x as bf16
__device__ __align__(16) u16   g_wT [EDIM * FDIM * MDIM];    // 64MB shared: w1^T then w2^T (bf16)
__device__ __align__(16) u16   g_h  [EDIM * CCAP * FDIM];    // 64MB h bf16 [e][c][f]
__device__ __align__(16) float g_eo [2 * EDIM * CCAP * MDIM];// 64MB f32 [ks][e][c][m]
__device__ float g_gates[S_TOK * EDIM];
__device__ int   g_idx1[S_TOK], g_idx2[S_TOK];
__device__ int   g_loc1[S_TOK], g_loc2[S_TOK];
__device__ float g_tg1[S_TOK],  g_tg2[S_TOK];
__device__ int   g_ts1[S_TOK],  g_ts2[S_TOK];
__device__ int   g_slot[EDIM * CCAP];

__device__ __forceinline__ u16 f2bf(float f) {
    union { float f; unsigned u; } c; c.f = f;
    unsigned r = c.u + 0x7FFFu + ((c.u >> 16) & 1u);
    return (u16)(r >> 16);
}
__device__ __forceinline__ void async16(const void* g, void* l) {
    __builtin_amdgcn_global_load_lds(
        (const __attribute__((address_space(1))) unsigned int*)g,
        (__attribute__((address_space(3))) unsigned int*)l, 16, 0, 0);
}

// ---------------- gate: logits -> softmax -> top1/top2; also x->bf16 ------
__global__ void gate_kernel(const float* __restrict__ x, const float* __restrict__ wg) {
    __shared__ float wgT[EDIM * MDIM];  // [e][m], 32KB
    const int tid = threadIdx.x, wave = tid >> 6, lane = tid & 63;
    for (int i = tid; i < EDIM * MDIM; i += 256) {
        int e = i >> 10, m = i & 1023;
        wgT[i] = wg[m * EDIM + e];
    }
    __syncthreads();
    const int s = blockIdx.x * 4 + wave;
    const float* xr = x + (size_t)s * MDIM;
    float lg[EDIM];
#pragma unroll
    for (int e = 0; e < EDIM; e++) lg[e] = 0.f;
#pragma unroll
    for (int j = 0; j < 4; j++) {
        int m0 = j * 256 + lane * 4;
        float4 xv = *(const float4*)(xr + m0);
        // fused x -> bf16 (replaces cvt_x kernel)
        u16x4 xb;
        xb[0] = f2bf(xv.x); xb[1] = f2bf(xv.y); xb[2] = f2bf(xv.z); xb[3] = f2bf(xv.w);
        *(u16x4*)(g_xb + (size_t)s * MDIM + m0) = xb;
#pragma unroll
        for (int e = 0; e < EDIM; e++) {
            float4 wv = *(const float4*)(&wgT[e * MDIM + m0]);
            lg[e] += xv.x * wv.x + xv.y * wv.y + xv.z * wv.z + xv.w * wv.w;
        }
    }
#pragma unroll
    for (int e = 0; e < EDIM; e++) {
        float v = lg[e];
        for (int o = 32; o >= 1; o >>= 1) v += __shfl_xor(v, o);
        lg[e] = v;
    }
    if (lane == 0) {
        float mx = lg[0];
#pragma unroll
        for (int e = 1; e < EDIM; e++) mx = fmaxf(mx, lg[e]);
        float ex[EDIM], sum = 0.f;
#pragma unroll
        for (int e = 0; e < EDIM; e++) { ex[e] = expf(lg[e] - mx); sum += ex[e]; }
        int i1 = 0; float b1 = lg[0];
#pragma unroll
        for (int e = 1; e < EDIM; e++) if (lg[e] > b1) { b1 = lg[e]; i1 = e; }
        int i2 = -1; float b2 = -3.4e38f;
#pragma unroll
        for (int e = 0; e < EDIM; e++) if (e != i1 && lg[e] > b2) { b2 = lg[e]; i2 = e; }
        float inv = 1.f / sum;
#pragma unroll
        for (int e = 0; e < EDIM; e++) g_gates[s * EDIM + e] = ex[e] * inv;
        g_idx1[s] = i1; g_idx2[s] = i2;
    }
}

// ---------------- scan: ranks, capacity, slots, l_aux --------------------
__global__ void scan_kernel(float* __restrict__ out_laux) {
    __shared__ float me_sh[EDIM];
    __shared__ int cnt_sh[EDIM];
    const int t = threadIdx.x, wave = t >> 6, lane = t & 63;
    if (t < EDIM) { me_sh[t] = 0.f; cnt_sh[t] = 0; }
    for (int i = t; i < EDIM * CCAP; i += 1024) g_slot[i] = -1;
    __syncthreads();
    float lm[EDIM]; int lc[EDIM];
#pragma unroll
    for (int e = 0; e < EDIM; e++) { lm[e] = 0.f; lc[e] = 0; }
    for (int j = 0; j < 4; j++) {
        int s = t + 1024 * j;
        const float* g = g_gates + (size_t)s * EDIM;
        int i1 = g_idx1[s];
#pragma unroll
        for (int e = 0; e < EDIM; e++) { lm[e] += g[e]; lc[e] += (i1 == e); }
    }
#pragma unroll
    for (int e = 0; e < EDIM; e++) {
        float v = lm[e]; int c = lc[e];
        for (int o = 32; o >= 1; o >>= 1) { v += __shfl_xor(v, o); c += __shfl_xor(c, o); }
        if (lane == 0) { atomicAdd(&me_sh[e], v); atomicAdd(&cnt_sh[e], c); }
    }
    __syncthreads();
    {   // rank phase: waves 0..7 -> mask1 per expert, 8..15 -> mask2
        int e = wave & 7;
        const int* idx = (wave < 8) ? g_idx1 : g_idx2;
        int* loc = (wave < 8) ? g_loc1 : g_loc2;
        int running = (wave < 8) ? 0 : cnt_sh[e];
        for (int s0 = 0; s0 < S_TOK; s0 += 64) {
            int v = idx[s0 + lane];
            bool f = (v == e);
            unsigned long long m = __ballot(f);
            int rank = __popcll(m & ((1ull << lane) - 1ull));
            if (f) loc[s0 + lane] = running + rank;
            running += __popcll(m);
        }
    }
    __syncthreads();
    for (int j = 0; j < 4; j++) {
        int s = t + 1024 * j;
        int e1 = g_idx1[s], e2 = g_idx2[s];
        int l1 = g_loc1[s], l2 = g_loc2[s];
        bool k1 = l1 < CCAP, k2 = l2 < CCAP;
        float G1 = k1 ? g_gates[s * EDIM + e1] : 0.f;
        float G2 = k2 ? g_gates[s * EDIM + e2] : 0.f;
        float den = G1 + G2; den = den < 1e-9f ? 1e-9f : den;
        g_tg1[s] = G1 / den; g_tg2[s] = G2 / den;
        g_ts1[s] = k1 ? (e1 * CCAP + l1) : -1;
        g_ts2[s] = k2 ? (e2 * CCAP + l2) : -1;
        if (k1) g_slot[e1 * CCAP + l1] = s;
        if (k2) g_slot[e2 * CCAP + l2] = s;
    }
    if (t == 0) {
        float la = 0.f;
        for (int e = 0; e < EDIM; e++)
            la += (me_sh[e] / (float)S_TOK) * ((float)cnt_sh[e] / (float)S_TOK);
        la *= (float)EDIM;  // (1/E)*sum * E*E
        out_laux[0] = la;
    }
}

// ---- LDS-tiled transpose+convert: f32 in [R][C] per expert -> bf16 g_wT [C][R]
template <int R, int C>
__global__ void transpose_cvt(const float* __restrict__ in) {
    __shared__ __align__(16) u16 t[64][72];   // pad 8 u16 keeps 16B-aligned rows
    const float* I = in + (size_t)blockIdx.z * R * C;
    u16* O = g_wT + (size_t)blockIdx.z * R * C;
    const int tid = threadIdx.x;
    const int c0 = blockIdx.x * 64, r0 = blockIdx.y * 64;
    const int rr = tid >> 4;          // 0..15
    const int cc = (tid & 15) * 4;    // 0,4,..,60
#pragma unroll
    for (int j = 0; j < 4; j++) {
        int r = rr + j * 16;
        float4 v = *(const float4*)(I + (size_t)(r0 + r) * C + c0 + cc);
        t[cc + 0][r] = f2bf(v.x);
        t[cc + 1][r] = f2bf(v.y);
        t[cc + 2][r] = f2bf(v.z);
        t[cc + 3][r] = f2bf(v.w);
    }
    __syncthreads();
    const int oc = tid >> 2;          // 0..63 : output row (= input col)
    const int orr = (tid & 3) * 16;   // 0,16,32,48
    u16x8 a = *(const u16x8*)(&t[oc][orr]);
    u16x8 b = *(const u16x8*)(&t[oc][orr + 8]);
    u16* dst = O + (size_t)(c0 + oc) * R + r0 + orr;
    *(u16x8*)(dst) = a;
    *(u16x8*)(dst + 8) = b;
}

// ======== shared GEMM machinery: 128x128 tile, BK=32, 3-deep counted dbuf =
// LDS tiles [128 rows][32 u16]; swizzle (both-sides): slot ^= (row>>1)&3.
#define GSTAGE(pA, pB)                                                      \
    {                                                                       \
        async16(gA0, (pA) + stA0); async16(gA1, (pA) + stA1);               \
        async16(gB0, (pB) + stA0); async16(gB1, (pB) + stA1);               \
        gA0 += 32; gA1 += 32; gB0 += 32; gB1 += 32;                         \
    }

#define GCOMPUTE(pA, pB)                                                    \
    {                                                                       \
        bf16x8 af[4], bfr[4];                                               \
        _Pragma("unroll")                                                   \
        for (int i = 0; i < 4; i++) {                                       \
            af[i]  = *(const bf16x8*)((pA) + (wm + i * 16 + lrow) * 32 + cr);\
            bfr[i] = *(const bf16x8*)((pB) + (wn + i * 16 + lrow) * 32 + cr);\
        }                                                                   \
        __builtin_amdgcn_s_setprio(1);                                      \
        _Pragma("unroll")                                                   \
        for (int mi = 0; mi < 4; mi++)                                      \
            _Pragma("unroll")                                               \
            for (int ni = 0; ni < 4; ni++)                                  \
                acc[mi][ni] = __builtin_amdgcn_mfma_f32_16x16x32_bf16(      \
                    af[mi], bfr[ni], acc[mi][ni], 0, 0, 0);                 \
        __builtin_amdgcn_s_setprio(0);                                      \
    }

#define BAR __builtin_amdgcn_s_barrier()

// 3-deep pipeline: stages t,t+1,t+2 in flight; vmcnt(8)=2 stages*4 loads.
#define GEMM_PIPELINE(T)                                                    \
    u16 *pa0 = As0, *pa1 = As1, *pa2 = As2;                                 \
    u16 *pb0 = Bs0, *pb1 = Bs1, *pb2 = Bs2;                                 \
    GSTAGE(pa0, pb0); GSTAGE(pa1, pb1); GSTAGE(pa2, pb2);                   \
    for (int t = 0; t < (T); ++t) {                                         \
        if (t < (T) - 2)       { asm volatile("s_waitcnt vmcnt(8)" ::: "memory"); } \
        else if (t == (T) - 2) { asm volatile("s_waitcnt vmcnt(4)" ::: "memory"); } \
        else                   { asm volatile("s_waitcnt vmcnt(0)" ::: "memory"); } \
        BAR;                                                                \
        GCOMPUTE(pa0, pb0);                                                 \
        BAR;                                                                \
        if (t + 3 < (T)) { GSTAGE(pa0, pb0); }                              \
        u16* tA = pa0; pa0 = pa1; pa1 = pa2; pa2 = tA;                      \
        u16* tB = pb0; pb0 = pb1; pb1 = pb2; pb2 = tB;                      \
    }

// ------- G1: h = relu(gather(xb) @ w1T)  [C,1024]x[1024,4096] -> bf16
__global__ __launch_bounds__(256, 3) void gemm_gather() {
    __shared__ __align__(16) u16 As0[4096], As1[4096], As2[4096];
    __shared__ __align__(16) u16 Bs0[4096], Bs1[4096], Bs2[4096];
    const int tid = threadIdx.x, wave = tid >> 6, lane = tid & 63;
    // XCD-chunked mapping: each XCD owns one expert (2048 blocks / 8)
    const int id = (blockIdx.x & 7) * 256 + (blockIdx.x >> 3);
    const int by = id & 7, bx = (id >> 3) & 31, e = id >> 8;
    const int scol = (((lane & 3) ^ ((lane >> 3) & 3)) * 8);
    const int stA0 = wave * 512, stA1 = 2048 + wave * 512;
    const int sb = e * CCAP + by * 128;
    int s0 = g_slot[sb + wave * 16 + (lane >> 2)];      if (s0 < 0) s0 = 0;
    int s1 = g_slot[sb + 64 + wave * 16 + (lane >> 2)]; if (s1 < 0) s1 = 0;
    const u16* gA0 = g_xb + (size_t)s0 * MDIM + scol;
    const u16* gA1 = g_xb + (size_t)s1 * MDIM + scol;
    const u16* Bb = g_wT + ((size_t)e * FDIM + bx * 128) * MDIM;
    const u16* gB0 = Bb + (size_t)(wave * 16 + (lane >> 2)) * MDIM + scol;
    const u16* gB1 = gB0 + (size_t)64 * MDIM;

    f32x4 acc[4][4];
#pragma unroll
    for (int i = 0; i < 4; i++)
#pragma unroll
        for (int j = 0; j < 4; j++) { f32x4 z = {0.f, 0.f, 0.f, 0.f}; acc[i][j] = z; }
    const int wm = (wave >> 1) * 64, wn = (wave & 1) * 64;
    const int lrow = lane & 15, lq = lane >> 4;
    const int cr = ((lq ^ ((lrow >> 1) & 3)) * 8);

    GEMM_PIPELINE(MDIM / 32)

    const int r0 = by * 128 + wm + lq * 4;
    const int c0 = bx * 128 + wn + lrow;
    u16* D = g_h + (size_t)e * CCAP * FDIM;
#pragma unroll
    for (int mi = 0; mi < 4; mi++)
#pragma unroll
        for (int v = 0; v < 4; v++) {
            size_t r = (size_t)(r0 + mi * 16 + v) * FDIM;
#pragma unroll
            for (int ni = 0; ni < 4; ni++) {
                float xv = acc[mi][ni][v];
                xv = xv > 0.f ? xv : 0.f;
                D[r + c0 + ni * 16] = f2bf(xv);
            }
        }
}

// ------- G2: eo[ks] = h[:, ks*2048+:2048] @ w2T[:, ks*2048+:2048]^T -> f32
__global__ __launch_bounds__(256, 3) void gemm_bt() {
    __shared__ __align__(16) u16 As0[4096], As1[4096], As2[4096];
    __shared__ __align__(16) u16 Bs0[4096], Bs1[4096], Bs2[4096];
    const int tid = threadIdx.x, wave = tid >> 6, lane = tid & 63;
    // XCD-chunked: each XCD owns one expert (both K-halves); 1024 blocks / 8
    const int id = (blockIdx.x & 7) * 128 + (blockIdx.x >> 3);
    const int by = id & 7, bx = (id >> 3) & 7, z = id >> 6;
    const int e = z >> 1, ks = z & 1;
    const int scol = (((lane & 3) ^ ((lane >> 3) & 3)) * 8);
    const int stA0 = wave * 512, stA1 = 2048 + wave * 512;
    const u16* Ab = g_h + (size_t)e * CCAP * FDIM + (size_t)(by * 128) * FDIM + ks * HALF_F;
    const u16* Bb = g_wT + (size_t)e * MDIM * FDIM + (size_t)(bx * 128) * FDIM + ks * HALF_F;
    const u16* gA0 = Ab + (size_t)(wave * 16 + (lane >> 2)) * FDIM + scol;
    const u16* gA1 = gA0 + (size_t)64 * FDIM;
    const u16* gB0 = Bb + (size_t)(wave * 16 + (lane >> 2)) * FDIM + scol;
    const u16* gB1 = gB0 + (size_t)64 * FDIM;

    f32x4 acc[4][4];
#pragma unroll
    for (int i = 0; i < 4; i++)
#pragma unroll
        for (int j = 0; j < 4; j++) { f32x4 z2 = {0.f, 0.f, 0.f, 0.f}; acc[i][j] = z2; }
    const int wm = (wave >> 1) * 64, wn = (wave & 1) * 64;
    const int lrow = lane & 15, lq = lane >> 4;
    const int cr = ((lq ^ ((lrow >> 1) & 3)) * 8);

    GEMM_PIPELINE(HALF_F / 32)

    const int r0 = by * 128 + wm + lq * 4;
    const int c0 = bx * 128 + wn + lrow;
    float* D = g_eo + (size_t)ks * (EDIM * CCAP * MDIM) + (size_t)e * CCAP * MDIM;
#pragma unroll
    for (int mi = 0; mi < 4; mi++)
#pragma unroll
        for (int v = 0; v < 4; v++) {
            size_t r = (size_t)(r0 + mi * 16 + v) * MDIM;
#pragma unroll
            for (int ni = 0; ni < 4; ni++)
                D[r + c0 + ni * 16] = acc[mi][ni][v];
        }
}

// ---------------- combine (f32 out), sums split-K partials ----------------
__global__ void combine_kernel(float* __restrict__ out) {
    const int s = blockIdx.x, t = threadIdx.x;
    constexpr size_t HALF = (size_t)EDIM * CCAP * MDIM;
    float g1 = g_tg1[s], g2 = g_tg2[s];
    int p1 = g_ts1[s], p2 = g_ts2[s];
    float a0 = 0.f, a1 = 0.f, a2 = 0.f, a3 = 0.f;
    if (p1 >= 0) {
        float4 v = ((const float4*)(g_eo + (size_t)p1 * MDIM))[t];
        float4 w = ((const float4*)(g_eo + HALF + (size_t)p1 * MDIM))[t];
        a0 = g1 * (v.x + w.x); a1 = g1 * (v.y + w.y);
        a2 = g1 * (v.z + w.z); a3 = g1 * (v.w + w.w);
    }
    if (p2 >= 0) {
        float4 v = ((const float4*)(g_eo + (size_t)p2 * MDIM))[t];
        float4 w = ((const float4*)(g_eo + HALF + (size_t)p2 * MDIM))[t];
        a0 += g2 * (v.x + w.x); a1 += g2 * (v.y + w.y);
        a2 += g2 * (v.z + w.z); a3 += g2 * (v.w + w.w);
    }
    float4 o; o.x = a0; o.y = a1; o.z = a2; o.w = a3;
    ((float4*)out)[(size_t)s * 256 + t] = o;
}

extern "C" void kernel_launch(void* const* d_in, const int* in_sizes, int n_in,
                              void* d_out, int out_size, void* d_ws, size_t ws_size,
                              hipStream_t stream) {
    const float* x  = (const float*)d_in[0];   // [4096][1024] f32
    const float* wg = (const float*)d_in[1];   // [1024][8]    f32
    const float* w1 = (const float*)d_in[2];   // [8][1024][4096] f32
    const float* w2 = (const float*)d_in[3];   // [8][4096][1024] f32
    float* out = (float*)d_out;                // 4194304 combined + 1 l_aux (f32)

    gate_kernel<<<dim3(S_TOK / 4), 256, 0, stream>>>(x, wg);
    scan_kernel<<<dim3(1), 1024, 0, stream>>>(out + 4194304);

    // w1 [e][1024 m][4096 f] -> g_wT [e][4096 f][1024 m]
    transpose_cvt<MDIM, FDIM><<<dim3(FDIM / 64, MDIM / 64, EDIM), 256, 0, stream>>>(w1);
    gemm_gather<<<dim3(2048), 256, 0, stream>>>();

    // w2 [e][4096 f][1024 m] -> g_wT [e][1024 m][4096 f]  (buffer reuse, serial stream)
    transpose_cvt<FDIM, MDIM><<<dim3(MDIM / 64, FDIM / 64, EDIM), 256, 0, stream>>>(w2);
    gemm_bt<<<dim3(1024), 256, 0, stream>>>();

    combine_kernel<<<dim3(S_TOK), 256, 0, stream>>>(out);
}

// Round 5
// 504.896 us; speedup vs baseline: 1.0712x; 1.0712x over previous
//
#include <hip/hip_runtime.h>
#include <hip/hip_bf16.h>

typedef unsigned short u16;
typedef short bf16x8 __attribute__((ext_vector_type(8)));
typedef float f32x4 __attribute__((ext_vector_type(4)));
typedef u16 u16x8 __attribute__((ext_vector_type(8)));
typedef u16 u16x4 __attribute__((ext_vector_type(4)));

#define S_TOK 4096
#define MDIM 1024
#define EDIM 8
#define FDIM 4096
#define CCAP 1024
#define HALF_F 2048

// ---- scratch in static device globals (200MB total) ----
__device__ __align__(16) u16   g_xb [S_TOK * MDIM];          // 8MB  x as bf16
__device__ __align__(16) u16   g_wT [EDIM * FDIM * MDIM];    // 64MB shared: w1^T then w2^T (bf16)
__device__ __align__(16) u16   g_h  [EDIM * CCAP * FDIM];    // 64MB h bf16 [e][c][f]
__device__ __align__(16) float g_eo [2 * EDIM * CCAP * MDIM];// 64MB f32 [ks][e][c][m]
__device__ float g_gates[S_TOK * EDIM];
__device__ int   g_idx1[S_TOK], g_idx2[S_TOK];
__device__ int   g_loc1[S_TOK], g_loc2[S_TOK];
__device__ float g_tg1[S_TOK],  g_tg2[S_TOK];
__device__ int   g_ts1[S_TOK],  g_ts2[S_TOK];
__device__ int   g_slot[EDIM * CCAP];

__device__ __forceinline__ u16 f2bf(float f) {
    union { float f; unsigned u; } c; c.f = f;
    unsigned r = c.u + 0x7FFFu + ((c.u >> 16) & 1u);
    return (u16)(r >> 16);
}
__device__ __forceinline__ void async16(const void* g, void* l) {
    __builtin_amdgcn_global_load_lds(
        (const __attribute__((address_space(1))) unsigned int*)g,
        (__attribute__((address_space(3))) unsigned int*)l, 16, 0, 0);
}

// ---------------- gate: logits -> softmax -> top1/top2; also x->bf16 ------
__global__ void gate_kernel(const float* __restrict__ x, const float* __restrict__ wg) {
    __shared__ float wgT[EDIM * MDIM];  // [e][m], 32KB
    const int tid = threadIdx.x, wave = tid >> 6, lane = tid & 63;
    for (int i = tid; i < EDIM * MDIM; i += 256) {
        int e = i >> 10, m = i & 1023;
        wgT[i] = wg[m * EDIM + e];
    }
    __syncthreads();
    const int s = blockIdx.x * 4 + wave;
    const float* xr = x + (size_t)s * MDIM;
    float lg[EDIM];
#pragma unroll
    for (int e = 0; e < EDIM; e++) lg[e] = 0.f;
#pragma unroll
    for (int j = 0; j < 4; j++) {
        int m0 = j * 256 + lane * 4;
        float4 xv = *(const float4*)(xr + m0);
        u16x4 xb;
        xb[0] = f2bf(xv.x); xb[1] = f2bf(xv.y); xb[2] = f2bf(xv.z); xb[3] = f2bf(xv.w);
        *(u16x4*)(g_xb + (size_t)s * MDIM + m0) = xb;
#pragma unroll
        for (int e = 0; e < EDIM; e++) {
            float4 wv = *(const float4*)(&wgT[e * MDIM + m0]);
            lg[e] += xv.x * wv.x + xv.y * wv.y + xv.z * wv.z + xv.w * wv.w;
        }
    }
#pragma unroll
    for (int e = 0; e < EDIM; e++) {
        float v = lg[e];
        for (int o = 32; o >= 1; o >>= 1) v += __shfl_xor(v, o);
        lg[e] = v;
    }
    if (lane == 0) {
        float mx = lg[0];
#pragma unroll
        for (int e = 1; e < EDIM; e++) mx = fmaxf(mx, lg[e]);
        float ex[EDIM], sum = 0.f;
#pragma unroll
        for (int e = 0; e < EDIM; e++) { ex[e] = expf(lg[e] - mx); sum += ex[e]; }
        int i1 = 0; float b1 = lg[0];
#pragma unroll
        for (int e = 1; e < EDIM; e++) if (lg[e] > b1) { b1 = lg[e]; i1 = e; }
        int i2 = -1; float b2 = -3.4e38f;
#pragma unroll
        for (int e = 0; e < EDIM; e++) if (e != i1 && lg[e] > b2) { b2 = lg[e]; i2 = e; }
        float inv = 1.f / sum;
#pragma unroll
        for (int e = 0; e < EDIM; e++) g_gates[s * EDIM + e] = ex[e] * inv;
        g_idx1[s] = i1; g_idx2[s] = i2;
    }
}

// ---------------- scan: ranks, capacity, slots, l_aux --------------------
__global__ void scan_kernel(float* __restrict__ out_laux) {
    __shared__ float me_sh[EDIM];
    __shared__ int cnt_sh[EDIM];
    const int t = threadIdx.x, wave = t >> 6, lane = t & 63;
    if (t < EDIM) { me_sh[t] = 0.f; cnt_sh[t] = 0; }
    for (int i = t; i < EDIM * CCAP; i += 1024) g_slot[i] = -1;
    __syncthreads();
    float lm[EDIM]; int lc[EDIM];
#pragma unroll
    for (int e = 0; e < EDIM; e++) { lm[e] = 0.f; lc[e] = 0; }
    for (int j = 0; j < 4; j++) {
        int s = t + 1024 * j;
        const float* g = g_gates + (size_t)s * EDIM;
        int i1 = g_idx1[s];
#pragma unroll
        for (int e = 0; e < EDIM; e++) { lm[e] += g[e]; lc[e] += (i1 == e); }
    }
#pragma unroll
    for (int e = 0; e < EDIM; e++) {
        float v = lm[e]; int c = lc[e];
        for (int o = 32; o >= 1; o >>= 1) { v += __shfl_xor(v, o); c += __shfl_xor(c, o); }
        if (lane == 0) { atomicAdd(&me_sh[e], v); atomicAdd(&cnt_sh[e], c); }
    }
    __syncthreads();
    {   // rank phase: waves 0..7 -> mask1 per expert, 8..15 -> mask2
        int e = wave & 7;
        const int* idx = (wave < 8) ? g_idx1 : g_idx2;
        int* loc = (wave < 8) ? g_loc1 : g_loc2;
        int running = (wave < 8) ? 0 : cnt_sh[e];
        for (int s0 = 0; s0 < S_TOK; s0 += 64) {
            int v = idx[s0 + lane];
            bool f = (v == e);
            unsigned long long m = __ballot(f);
            int rank = __popcll(m & ((1ull << lane) - 1ull));
            if (f) loc[s0 + lane] = running + rank;
            running += __popcll(m);
        }
    }
    __syncthreads();
    for (int j = 0; j < 4; j++) {
        int s = t + 1024 * j;
        int e1 = g_idx1[s], e2 = g_idx2[s];
        int l1 = g_loc1[s], l2 = g_loc2[s];
        bool k1 = l1 < CCAP, k2 = l2 < CCAP;
        float G1 = k1 ? g_gates[s * EDIM + e1] : 0.f;
        float G2 = k2 ? g_gates[s * EDIM + e2] : 0.f;
        float den = G1 + G2; den = den < 1e-9f ? 1e-9f : den;
        g_tg1[s] = G1 / den; g_tg2[s] = G2 / den;
        g_ts1[s] = k1 ? (e1 * CCAP + l1) : -1;
        g_ts2[s] = k2 ? (e2 * CCAP + l2) : -1;
        if (k1) g_slot[e1 * CCAP + l1] = s;
        if (k2) g_slot[e2 * CCAP + l2] = s;
    }
    if (t == 0) {
        float la = 0.f;
        for (int e = 0; e < EDIM; e++)
            la += (me_sh[e] / (float)S_TOK) * ((float)cnt_sh[e] / (float)S_TOK);
        la *= (float)EDIM;
        out_laux[0] = la;
    }
}

// ---- LDS-tiled transpose+convert: f32 in [R][C] per expert -> bf16 g_wT [C][R]
template <int R, int C>
__global__ void transpose_cvt(const float* __restrict__ in) {
    __shared__ __align__(16) u16 t[64][72];
    const float* I = in + (size_t)blockIdx.z * R * C;
    u16* O = g_wT + (size_t)blockIdx.z * R * C;
    const int tid = threadIdx.x;
    const int c0 = blockIdx.x * 64, r0 = blockIdx.y * 64;
    const int rr = tid >> 4;
    const int cc = (tid & 15) * 4;
#pragma unroll
    for (int j = 0; j < 4; j++) {
        int r = rr + j * 16;
        float4 v = *(const float4*)(I + (size_t)(r0 + r) * C + c0 + cc);
        t[cc + 0][r] = f2bf(v.x);
        t[cc + 1][r] = f2bf(v.y);
        t[cc + 2][r] = f2bf(v.z);
        t[cc + 3][r] = f2bf(v.w);
    }
    __syncthreads();
    const int oc = tid >> 2;
    const int orr = (tid & 3) * 16;
    u16x8 a = *(const u16x8*)(&t[oc][orr]);
    u16x8 b = *(const u16x8*)(&t[oc][orr + 8]);
    u16* dst = O + (size_t)(c0 + oc) * R + r0 + orr;
    *(u16x8*)(dst) = a;
    *(u16x8*)(dst + 8) = b;
}

// ======== 256x256 tile, BK=32, 8 waves, triple-buffered ring, phase-split =
// LDS: A ring 3 x [256][32] u16 (16KB each) + B ring 3 x same = 96KB.
// Swizzle (verified in R3, conflicts=0): read slot = lq ^ ((lrow>>1)&3);
// write side pre-swizzles the GLOBAL source column (LDS dest stays linear).
#define ST_A0(s) { async16(pA0, ldsA + (s)*8192 + wid*512);        pA0 += 32; }
#define ST_A1(s) { async16(pA1, ldsA + (s)*8192 + 4096 + wid*512); pA1 += 32; }
#define ST_B0(s) { async16(pB0, ldsB + (s)*8192 + wid*512);        pB0 += 32; }
#define ST_B1(s) { async16(pB1, ldsB + (s)*8192 + 4096 + wid*512); pB1 += 32; }

#define GEMM256_BODY(NT)                                                     \
    f32x4 acc[8][4];                                                         \
    _Pragma("unroll")                                                        \
    for (int i = 0; i < 8; i++)                                              \
        _Pragma("unroll")                                                    \
        for (int j = 0; j < 4; j++) { f32x4 z = {0.f,0.f,0.f,0.f}; acc[i][j] = z; } \
    ST_A0(0); ST_A1(0); ST_B0(0); ST_B1(0);                                  \
    ST_A0(1); ST_A1(1); ST_B0(1); ST_B1(1);                                  \
    asm volatile("s_waitcnt vmcnt(4)" ::: "memory");                         \
    __builtin_amdgcn_s_barrier();                                            \
    int s = 0;                                                               \
    for (int u = 0; u < (NT); ++u) {                                         \
        int ps = s + 2; if (ps >= 3) ps -= 3;                                \
        const u16* A = ldsA + s * 8192;                                      \
        const u16* B = ldsB + s * 8192;                                      \
        bf16x8 af[4], bfr[4];                                                \
        _Pragma("unroll")                                                    \
        for (int i = 0; i < 4; i++)                                          \
            af[i] = *(const bf16x8*)(A + (wr*128 + i*16 + lrow)*32 + cr);    \
        _Pragma("unroll")                                                    \
        for (int i = 0; i < 4; i++)                                          \
            bfr[i] = *(const bf16x8*)(B + (wc*64 + i*16 + lrow)*32 + cr);    \
        if (u + 2 < (NT)) { ST_A0(ps); ST_A1(ps); }                          \
        __builtin_amdgcn_s_barrier();                                        \
        asm volatile("s_waitcnt lgkmcnt(0)" ::: "memory");                   \
        __builtin_amdgcn_sched_barrier(0);                                   \
        __builtin_amdgcn_s_setprio(1);                                       \
        _Pragma("unroll")                                                    \
        for (int i = 0; i < 4; i++)                                          \
            _Pragma("unroll")                                                \
            for (int j = 0; j < 4; j++)                                      \
                acc[i][j] = __builtin_amdgcn_mfma_f32_16x16x32_bf16(         \
                    af[i], bfr[j], acc[i][j], 0, 0, 0);                      \
        __builtin_amdgcn_s_setprio(0);                                       \
        __builtin_amdgcn_s_barrier();                                        \
        _Pragma("unroll")                                                    \
        for (int i = 0; i < 4; i++)                                          \
            af[i] = *(const bf16x8*)(A + (wr*128 + 64 + i*16 + lrow)*32 + cr);\
        if (u + 2 < (NT)) { ST_B0(ps); ST_B1(ps); }                          \
        __builtin_amdgcn_s_barrier();                                        \
        asm volatile("s_waitcnt lgkmcnt(0)" ::: "memory");                   \
        __builtin_amdgcn_sched_barrier(0);                                   \
        __builtin_amdgcn_s_setprio(1);                                       \
        _Pragma("unroll")                                                    \
        for (int i = 0; i < 4; i++)                                          \
            _Pragma("unroll")                                                \
            for (int j = 0; j < 4; j++)                                      \
                acc[4+i][j] = __builtin_amdgcn_mfma_f32_16x16x32_bf16(       \
                    af[i], bfr[j], acc[4+i][j], 0, 0, 0);                    \
        __builtin_amdgcn_s_setprio(0);                                       \
        if (u + 2 < (NT))      { asm volatile("s_waitcnt vmcnt(4)" ::: "memory"); } \
        else if (u + 1 < (NT)) { asm volatile("s_waitcnt vmcnt(0)" ::: "memory"); } \
        __builtin_amdgcn_s_barrier();                                        \
        s = s + 1; if (s == 3) s = 0;                                        \
    }

// ------- G1: h = relu(gather(xb) @ w1T)  [1024,1024]x[1024,4096] -> bf16
__global__ __launch_bounds__(512, 1) void gemm_gather() {
    __shared__ __align__(16) u16 lds[49152];   // 96KB
    u16* ldsA = lds;
    u16* ldsB = lds + 24576;
    const int tid = threadIdx.x, wid = tid >> 6, lane = tid & 63;
    const int wr = wid >> 2, wc = wid & 3;
    const int lrow = lane & 15, lq = lane >> 4;
    const int cr   = (lq ^ ((lrow >> 1) & 3)) * 8;
    const int scol = ((lane & 3) ^ ((lane >> 3) & 3)) * 8;
    const int srow = tid >> 2;                  // 0..127
    // XCD-chunked: 512 blocks, 64/XCD = one expert per XCD
    const int id = (blockIdx.x & 7) * 64 + (blockIdx.x >> 3);
    const int by = id & 3, bx = (id >> 2) & 15, e = id >> 6;

    const int sb = e * CCAP + by * 256;
    int t0 = g_slot[sb + srow];        if (t0 < 0) t0 = 0;
    int t1 = g_slot[sb + 128 + srow];  if (t1 < 0) t1 = 0;
    const u16* pA0 = g_xb + (size_t)t0 * MDIM + scol;
    const u16* pA1 = g_xb + (size_t)t1 * MDIM + scol;
    const u16* pB0 = g_wT + ((size_t)e * FDIM + bx * 256 + srow) * MDIM + scol;
    const u16* pB1 = pB0 + (size_t)128 * MDIM;

    GEMM256_BODY(MDIM / 32)

    const int r0 = by * 256 + wr * 128 + lq * 4;
    const int c0 = bx * 256 + wc * 64 + lrow;
    u16* D = g_h + (size_t)e * CCAP * FDIM;
#pragma unroll
    for (int fm = 0; fm < 8; fm++)
#pragma unroll
        for (int v = 0; v < 4; v++) {
            size_t r = (size_t)(r0 + fm * 16 + v) * FDIM;
#pragma unroll
            for (int fn = 0; fn < 4; fn++) {
                float xv = acc[fm][fn][v];
                xv = xv > 0.f ? xv : 0.f;
                D[r + c0 + fn * 16] = f2bf(xv);
            }
        }
}

// ------- G2: eo[ks] = h[:, ks*2048+:2048] @ w2T[:, ks*2048+:2048]^T -> f32
__global__ __launch_bounds__(512, 1) void gemm_bt() {
    __shared__ __align__(16) u16 lds[49152];   // 96KB
    u16* ldsA = lds;
    u16* ldsB = lds + 24576;
    const int tid = threadIdx.x, wid = tid >> 6, lane = tid & 63;
    const int wr = wid >> 2, wc = wid & 3;
    const int lrow = lane & 15, lq = lane >> 4;
    const int cr   = (lq ^ ((lrow >> 1) & 3)) * 8;
    const int scol = ((lane & 3) ^ ((lane >> 3) & 3)) * 8;
    const int srow = tid >> 2;
    // XCD-chunked: 256 blocks, 32/XCD = one expert (both K-halves) per XCD
    const int id = (blockIdx.x & 7) * 32 + (blockIdx.x >> 3);
    const int by = id & 3, bx = (id >> 2) & 3, z = id >> 4;
    const int e = z >> 1, ks = z & 1;

    const u16* pA0 = g_h + ((size_t)e * CCAP + by * 256 + srow) * FDIM + ks * HALF_F + scol;
    const u16* pA1 = pA0 + (size_t)128 * FDIM;
    const u16* pB0 = g_wT + ((size_t)e * MDIM + bx * 256 + srow) * FDIM + ks * HALF_F + scol;
    const u16* pB1 = pB0 + (size_t)128 * FDIM;

    GEMM256_BODY(HALF_F / 32)

    const int r0 = by * 256 + wr * 128 + lq * 4;
    const int c0 = bx * 256 + wc * 64 + lrow;
    float* D = g_eo + (size_t)ks * (EDIM * CCAP * MDIM) + (size_t)e * CCAP * MDIM;
#pragma unroll
    for (int fm = 0; fm < 8; fm++)
#pragma unroll
        for (int v = 0; v < 4; v++) {
            size_t r = (size_t)(r0 + fm * 16 + v) * MDIM;
#pragma unroll
            for (int fn = 0; fn < 4; fn++)
                D[r + c0 + fn * 16] = acc[fm][fn][v];
        }
}

// ---------------- combine (f32 out), sums split-K partials ----------------
__global__ void combine_kernel(float* __restrict__ out) {
    const int s = blockIdx.x, t = threadIdx.x;
    constexpr size_t HALF = (size_t)EDIM * CCAP * MDIM;
    float g1 = g_tg1[s], g2 = g_tg2[s];
    int p1 = g_ts1[s], p2 = g_ts2[s];
    float a0 = 0.f, a1 = 0.f, a2 = 0.f, a3 = 0.f;
    if (p1 >= 0) {
        float4 v = ((const float4*)(g_eo + (size_t)p1 * MDIM))[t];
        float4 w = ((const float4*)(g_eo + HALF + (size_t)p1 * MDIM))[t];
        a0 = g1 * (v.x + w.x); a1 = g1 * (v.y + w.y);
        a2 = g1 * (v.z + w.z); a3 = g1 * (v.w + w.w);
    }
    if (p2 >= 0) {
        float4 v = ((const float4*)(g_eo + (size_t)p2 * MDIM))[t];
        float4 w = ((const float4*)(g_eo + HALF + (size_t)p2 * MDIM))[t];
        a0 += g2 * (v.x + w.x); a1 += g2 * (v.y + w.y);
        a2 += g2 * (v.z + w.z); a3 += g2 * (v.w + w.w);
    }
    float4 o; o.x = a0; o.y = a1; o.z = a2; o.w = a3;
    ((float4*)out)[(size_t)s * 256 + t] = o;
}

extern "C" void kernel_launch(void* const* d_in, const int* in_sizes, int n_in,
                              void* d_out, int out_size, void* d_ws, size_t ws_size,
                              hipStream_t stream) {
    const float* x  = (const float*)d_in[0];   // [4096][1024] f32
    const float* wg = (const float*)d_in[1];   // [1024][8]    f32
    const float* w1 = (const float*)d_in[2];   // [8][1024][4096] f32
    const float* w2 = (const float*)d_in[3];   // [8][4096][1024] f32
    float* out = (float*)d_out;                // 4194304 combined + 1 l_aux (f32)

    gate_kernel<<<dim3(S_TOK / 4), 256, 0, stream>>>(x, wg);
    scan_kernel<<<dim3(1), 1024, 0, stream>>>(out + 4194304);

    // w1 [e][1024 m][4096 f] -> g_wT [e][4096 f][1024 m]
    transpose_cvt<MDIM, FDIM><<<dim3(FDIM / 64, MDIM / 64, EDIM), 256, 0, stream>>>(w1);
    gemm_gather<<<dim3(512), 512, 0, stream>>>();

    // w2 [e][4096 f][1024 m] -> g_wT [e][1024 m][4096 f]  (buffer reuse, serial stream)
    transpose_cvt<FDIM, MDIM><<<dim3(MDIM / 64, FDIM / 64, EDIM), 256, 0, stream>>>(w2);
    gemm_bt<<<dim3(256), 512, 0, stream>>>();

    combine_kernel<<<dim3(S_TOK), 256, 0, stream>>>(out);
}